// Round 1
// baseline (5233.955 us; speedup 1.0000x reference)
//
#include <hip/hip_runtime.h>
#include <hip/hip_bf16.h>
#include <stdint.h>

#define EDIM 300
#define KP   320      // padded E for MFMA K-loop
#define HDIM 256
#define G4H  1024
#define NB   2048     // both directions' gates
#define TAGS 9
#define BATCH 64
#define SEQ  512
#define MROWS (SEQ*BATCH)   // 32768

typedef _Float16 f16;
typedef _Float16 half2_t __attribute__((ext_vector_type(2)));
typedef _Float16 half8_t __attribute__((ext_vector_type(8)));
typedef float    floatx4 __attribute__((ext_vector_type(4)));

__device__ __forceinline__ float fdot2(uint32_t w, uint32_t h, float acc) {
#if __has_builtin(__builtin_amdgcn_fdot2)
    return __builtin_amdgcn_fdot2(__builtin_bit_cast(half2_t, w),
                                  __builtin_bit_cast(half2_t, h), acc, false);
#else
    half2_t a = __builtin_bit_cast(half2_t, w), b = __builtin_bit_cast(half2_t, h);
    return acc + (float)a[0]*(float)b[0] + (float)a[1]*(float)b[1];
#endif
}

// ---- pack input-projection weights [n<1024: wih_f | n>=1024: wih_b], K padded to 320, + fused bias
__global__ void k_pack_wih(const float* __restrict__ wih_f, const float* __restrict__ wih_b,
                           const float* __restrict__ bih_f, const float* __restrict__ bhh_f,
                           const float* __restrict__ bih_b, const float* __restrict__ bhh_b,
                           f16* __restrict__ wpack, float* __restrict__ bias2) {
    int n = blockIdx.x;
    const float* src = (n < G4H) ? (wih_f + (long)n*EDIM) : (wih_b + (long)(n-G4H)*EDIM);
    for (int k = threadIdx.x; k < KP; k += 64)
        wpack[(long)n*KP + k] = (k < EDIM) ? (f16)src[k] : (f16)0.f;
    if (threadIdx.x == 0)
        bias2[n] = (n < G4H) ? (bih_f[n] + bhh_f[n]) : (bih_b[n-G4H] + bhh_b[n-G4H]);
}

// ---- pack recurrent weights into [dir][k2][j][2] f16 (k-pairs for v_dot2, j coalesced)
__global__ void k_pack_whh(const float* __restrict__ whh_f, const float* __restrict__ whh_b,
                           f16* __restrict__ whhp) {
    int fidx = blockIdx.x*256 + threadIdx.x;   // < 524288
    int d  = fidx >> 18;
    int r  = fidx & 262143;
    int k2 = r >> 11;
    int r2 = r & 2047;
    int j  = r2 >> 1;
    int p  = r2 & 1;
    const float* w = d ? whh_b : whh_f;
    whhp[fidx] = (f16)w[(long)j*HDIM + 2*k2 + p];
}

// ---- embedding gather, f16, row m = t*64+b, padded to KP
__global__ void k_gather(const int* __restrict__ sentence, const float* __restrict__ embed,
                         f16* __restrict__ xg) {
    int m = blockIdx.x;
    int t = m >> 6, b = m & 63;
    int tok = sentence[b*SEQ + t];
    const float* row = embed + (long)tok*EDIM;
    for (int e = threadIdx.x; e < KP; e += 64)
        xg[(long)m*KP + e] = (e < EDIM) ? (f16)row[e] : (f16)0.f;
}

// ---- xproj = xg @ wpack^T + bias2, f16 MFMA GEMM, M=32768 N=2048 K=320
__launch_bounds__(256)
__global__ void k_gemm_xproj(const f16* __restrict__ xg, const f16* __restrict__ wpack,
                             const float* __restrict__ bias2, f16* __restrict__ xproj) {
    __shared__ __align__(16) f16 As[128*40];
    __shared__ __align__(16) f16 Bs[128*40];
    int tid = threadIdx.x;
    int bm = blockIdx.x, bn = blockIdx.y;
    int wid = tid >> 6, lane = tid & 63;
    int waveM = wid & 1, waveN = wid >> 1;
    int quad = lane >> 4, mlo = lane & 15;
    floatx4 acc[4][4] = {};
    for (int k0 = 0; k0 < KP; k0 += 32) {
        for (int it = 0; it < 2; ++it) {
            int c = tid + it*256;
            int row = c >> 2, ko = (c & 3)*8;
            *(uint4*)(&As[row*40 + ko]) = *(const uint4*)(&xg[(long)(bm*128+row)*KP + k0 + ko]);
            *(uint4*)(&Bs[row*40 + ko]) = *(const uint4*)(&wpack[(long)(bn*128+row)*KP + k0 + ko]);
        }
        __syncthreads();
        half8_t af[4], bf[4];
        #pragma unroll
        for (int i = 0; i < 4; ++i)
            af[i] = *(const half8_t*)(&As[(waveM*64 + i*16 + mlo)*40 + quad*8]);
        #pragma unroll
        for (int j = 0; j < 4; ++j)
            bf[j] = *(const half8_t*)(&Bs[(waveN*64 + j*16 + mlo)*40 + quad*8]);
        #pragma unroll
        for (int i = 0; i < 4; ++i)
            #pragma unroll
            for (int j = 0; j < 4; ++j)
                acc[i][j] = __builtin_amdgcn_mfma_f32_16x16x32_f16(af[i], bf[j], acc[i][j], 0, 0, 0);
        __syncthreads();
    }
    #pragma unroll
    for (int i = 0; i < 4; ++i)
        #pragma unroll
        for (int j = 0; j < 4; ++j) {
            int col = bn*128 + waveN*64 + j*16 + mlo;
            float bv = bias2[col];
            #pragma unroll
            for (int r = 0; r < 4; ++r) {
                int row = bm*128 + waveM*64 + i*16 + quad*4 + r;
                xproj[(long)row*NB + col] = (f16)(acc[i][j][r] + bv);
            }
        }
}

// ---- LSTM recurrence: WG = (dir, 4 batch rows), 1024 threads (thread = gate j),
// h as f16 pairs in LDS [k2][b][2] so one ds_read_b128 feeds 4 batch dot2s.
__launch_bounds__(1024)
__global__ void k_recur(const f16* __restrict__ xproj, const f16* __restrict__ whhp,
                        f16* __restrict__ hcat) {
    __shared__ uint4 hb2q[128];        // [k2]{b0,b1,b2,b3} each uint = 2 f16 (k=2k2,2k2+1)
    __shared__ float gbuf[4][1024];
    int dir = blockIdx.x & 1, bg = blockIdx.x >> 1;
    int b0 = bg*4;
    int tid = threadIdx.x;             // = gate index j
    const uint32_t* wbase = (const uint32_t*)whhp + (long)dir*131072 + tid;
    const f16* xcol = xproj + dir*G4H + tid;
    float c0=0.f, c1=0.f, c2=0.f, c3=0.f;
    if (tid < 128) hb2q[tid] = make_uint4(0,0,0,0);
    __syncthreads();
    for (int s = 0; s < SEQ; ++s) {
        int t = dir ? (SEQ-1-s) : s;
        long mbase = (long)(t*64 + b0);
        float a0=0.f, a1=0.f, a2=0.f, a3=0.f;
        #pragma unroll 8
        for (int k2 = 0; k2 < 128; ++k2) {
            uint32_t w = wbase[(long)k2*1024];
            uint4 hv = hb2q[k2];
            a0 = fdot2(w, hv.x, a0);
            a1 = fdot2(w, hv.y, a1);
            a2 = fdot2(w, hv.z, a2);
            a3 = fdot2(w, hv.w, a3);
        }
        gbuf[0][tid] = a0 + (float)xcol[(mbase+0)*NB];
        gbuf[1][tid] = a1 + (float)xcol[(mbase+1)*NB];
        gbuf[2][tid] = a2 + (float)xcol[(mbase+2)*NB];
        gbuf[3][tid] = a3 + (float)xcol[(mbase+3)*NB];
        __syncthreads();               // gbuf ready; all dot-reads of hb2q done
        if (tid < HDIM) {
            f16* hb2h = (f16*)hb2q;
            int kk = tid;
            #pragma unroll
            for (int bb = 0; bb < 4; ++bb) {
                float gi = gbuf[bb][kk],        gf = gbuf[bb][HDIM+kk];
                float gg = gbuf[bb][2*HDIM+kk], go = gbuf[bb][3*HDIM+kk];
                float si = 1.f/(1.f+__expf(-gi));
                float sf = 1.f/(1.f+__expf(-gf));
                float so = 1.f/(1.f+__expf(-go));
                float cprev = (bb==0)?c0:(bb==1)?c1:(bb==2)?c2:c3;
                float cc = sf*cprev + si*tanhf(gg);
                if (bb==0) c0=cc; else if (bb==1) c1=cc; else if (bb==2) c2=cc; else c3=cc;
                float h = so*tanhf(cc);
                hb2h[(kk>>1)*8 + bb*2 + (kk&1)] = (f16)h;
                hcat[(mbase+bb)*512 + dir*HDIM + kk] = (f16)h;
            }
        }
        __syncthreads();               // new h visible before next step's dots
    }
}

// ---- emissions: one wave per (t,b) row; lanes split K=512; 9 shuffle-reduced dots
__launch_bounds__(256)
__global__ void k_emis(const f16* __restrict__ hcat, const float* __restrict__ w_out,
                       const float* __restrict__ b_out, float* __restrict__ emis) {
    int r = blockIdx.x*4 + (threadIdx.x >> 6);
    int lane = threadIdx.x & 63;
    float hv[8];
    #pragma unroll
    for (int i = 0; i < 8; ++i) hv[i] = (float)hcat[(long)r*512 + lane + i*64];
    for (int tag = 0; tag < TAGS; ++tag) {
        float acc = 0.f;
        #pragma unroll
        for (int i = 0; i < 8; ++i) acc += hv[i]*w_out[tag*512 + lane + i*64];
        for (int off = 32; off; off >>= 1) acc += __shfl_xor(acc, off);
        if (lane == 0) emis[(long)r*TAGS + tag] = acc + b_out[tag];
    }
}

// ---- CRF: one wave per batch row. Gold score (lane-parallel over t) + forward logZ
// (lanes 0..8 hold alpha[j], shuffle-broadcast logsumexp over 9 prev tags).
__launch_bounds__(256)
__global__ void k_crf(const float* __restrict__ emis, const int* __restrict__ tags,
                      const int* __restrict__ mask, const float* __restrict__ start_trans,
                      const float* __restrict__ end_trans, const float* __restrict__ trans,
                      float* __restrict__ out) {
    int b = blockIdx.x*4 + (threadIdx.x >> 6);
    int lane = threadIdx.x & 63;
    int len = 0;
    #pragma unroll
    for (int i = 0; i < 8; ++i) len += mask[b*SEQ + lane + i*64];
    for (int off = 32; off; off >>= 1) len += __shfl_xor(len, off);
    float sc = 0.f;
    for (int i = 0; i < 8; ++i) {
        int t = 1 + lane + i*64;
        if (t < SEQ && mask[b*SEQ + t]) {
            int tp = tags[b*SEQ + t - 1], tc = tags[b*SEQ + t];
            sc += trans[tp*TAGS + tc] + emis[(long)(t*64 + b)*TAGS + tc];
        }
    }
    for (int off = 32; off; off >>= 1) sc += __shfl_xor(sc, off);
    int tag0 = tags[b*SEQ];
    sc += start_trans[tag0] + emis[(long)b*TAGS + tag0];
    sc += end_trans[tags[b*SEQ + len - 1]];
    // logZ
    bool act = lane < TAGS;
    int j = act ? lane : 0;
    float tcol[TAGS];
    #pragma unroll
    for (int i = 0; i < TAGS; ++i) tcol[i] = trans[i*TAGS + j];
    float alpha = act ? (start_trans[j] + emis[(long)b*TAGS + j]) : -1e30f;
    for (int t = 1; t < SEQ; ++t) {
        int mt = mask[b*SEQ + t];
        float em = emis[(long)(t*64 + b)*TAGS + j];
        float v[TAGS], mx = -1e30f;
        #pragma unroll
        for (int i = 0; i < TAGS; ++i) { v[i] = __shfl(alpha, i) + tcol[i]; mx = fmaxf(mx, v[i]); }
        float ss = 0.f;
        #pragma unroll
        for (int i = 0; i < TAGS; ++i) ss += __expf(v[i] - mx);
        float nxt = mx + __logf(ss) + em;
        if (mt && act) alpha = nxt;
    }
    float fv = act ? (alpha + end_trans[j]) : -1e30f;
    float mx = fv;
    for (int off = 32; off; off >>= 1) mx = fmaxf(mx, __shfl_xor(mx, off));
    float ss = act ? __expf(fv - mx) : 0.f;
    for (int off = 32; off; off >>= 1) ss += __shfl_xor(ss, off);
    float logZ = mx + __logf(ss);
    if (lane == 0) atomicAdd(out, (logZ - sc) * (1.0f/BATCH));
}

extern "C" void kernel_launch(void* const* d_in, const int* in_sizes, int n_in,
                              void* d_out, int out_size, void* d_ws, size_t ws_size,
                              hipStream_t stream) {
    const int*   sentence    = (const int*)  d_in[0];
    const int*   tags        = (const int*)  d_in[1];
    const float* embed       = (const float*)d_in[2];
    const float* wih_f       = (const float*)d_in[3];
    const float* whh_f       = (const float*)d_in[4];
    const float* bih_f       = (const float*)d_in[5];
    const float* bhh_f       = (const float*)d_in[6];
    const float* wih_b       = (const float*)d_in[7];
    const float* whh_b       = (const float*)d_in[8];
    const float* bih_b       = (const float*)d_in[9];
    const float* bhh_b       = (const float*)d_in[10];
    const float* w_out       = (const float*)d_in[11];
    const float* b_out       = (const float*)d_in[12];
    const float* start_trans = (const float*)d_in[13];
    const float* end_trans   = (const float*)d_in[14];
    const float* trans       = (const float*)d_in[15];
    const int*   mask        = (const int*)  d_in[16];

    char* ws = (char*)d_ws;
    f16*   xg    = (f16*)ws;   ws += (size_t)MROWS*KP*2;      // 20.97 MB
    f16*   wpack = (f16*)ws;   ws += (size_t)NB*KP*2;         // 1.31 MB
    float* bias2 = (float*)ws; ws += (size_t)NB*4;            // 8 KB
    f16*   whhp  = (f16*)ws;   ws += (size_t)2*262144*2;      // 1.05 MB
    f16*   xproj = (f16*)ws;   ws += (size_t)MROWS*NB*2;      // 134.2 MB
    f16*   hcat  = (f16*)ws;   ws += (size_t)MROWS*512*2;     // 33.55 MB
    float* emis  = (float*)ws; ws += (size_t)MROWS*TAGS*4;    // 1.18 MB

    hipLaunchKernelGGL(k_pack_wih, dim3(NB), dim3(64), 0, stream,
                       wih_f, wih_b, bih_f, bhh_f, bih_b, bhh_b, wpack, bias2);
    hipLaunchKernelGGL(k_pack_whh, dim3(2048), dim3(256), 0, stream, whh_f, whh_b, whhp);
    hipLaunchKernelGGL(k_gather, dim3(MROWS), dim3(64), 0, stream, sentence, embed, xg);
    hipLaunchKernelGGL(k_gemm_xproj, dim3(256,16), dim3(256), 0, stream, xg, wpack, bias2, xproj);
    hipLaunchKernelGGL(k_recur, dim3(32), dim3(1024), 0, stream, xproj, whhp, hcat);
    hipLaunchKernelGGL(k_emis, dim3(MROWS/4), dim3(256), 0, stream, hcat, w_out, b_out, emis);
    hipMemsetAsync(d_out, 0, sizeof(float), stream);
    hipLaunchKernelGGL(k_crf, dim3(BATCH/4), dim3(256), 0, stream,
                       emis, tags, mask, start_trans, end_trans, trans, (float*)d_out);
}

// Round 2
// 1752.358 us; speedup vs baseline: 2.9868x; 2.9868x over previous
//
#include <hip/hip_runtime.h>
#include <hip/hip_bf16.h>
#include <stdint.h>

#define EDIM 300
#define KP   320      // padded E for MFMA K-loop
#define HDIM 256
#define G4H  1024
#define NB   2048     // both directions' gates
#define TAGS 9
#define BATCH 64
#define SEQ  512
#define MROWS (SEQ*BATCH)   // 32768

typedef _Float16 f16;
typedef _Float16 half2_t __attribute__((ext_vector_type(2)));
typedef _Float16 half8_t __attribute__((ext_vector_type(8)));
typedef float    floatx4 __attribute__((ext_vector_type(4)));

__device__ __forceinline__ float fdot2(uint32_t w, uint32_t h, float acc) {
#if __has_builtin(__builtin_amdgcn_fdot2)
    return __builtin_amdgcn_fdot2(__builtin_bit_cast(half2_t, w),
                                  __builtin_bit_cast(half2_t, h), acc, false);
#else
    half2_t a = __builtin_bit_cast(half2_t, w), b = __builtin_bit_cast(half2_t, h);
    return acc + (float)a[0]*(float)b[0] + (float)a[1]*(float)b[1];
#endif
}

// ---- pack input-projection weights [n<1024: wih_f | n>=1024: wih_b], K padded to 320, + fused bias
__global__ void k_pack_wih(const float* __restrict__ wih_f, const float* __restrict__ wih_b,
                           const float* __restrict__ bih_f, const float* __restrict__ bhh_f,
                           const float* __restrict__ bih_b, const float* __restrict__ bhh_b,
                           f16* __restrict__ wpack, float* __restrict__ bias2) {
    int n = blockIdx.x;
    const float* src = (n < G4H) ? (wih_f + (long)n*EDIM) : (wih_b + (long)(n-G4H)*EDIM);
    for (int k = threadIdx.x; k < KP; k += 64)
        wpack[(long)n*KP + k] = (k < EDIM) ? (f16)src[k] : (f16)0.f;
    if (threadIdx.x == 0)
        bias2[n] = (n < G4H) ? (bih_f[n] + bhh_f[n]) : (bih_b[n-G4H] + bhh_b[n-G4H]);
}

// ---- pack recurrent weights into [dir][k2][j][2] f16 (k-pairs for v_dot2, j coalesced)
__global__ void k_pack_whh(const float* __restrict__ whh_f, const float* __restrict__ whh_b,
                           f16* __restrict__ whhp) {
    int fidx = blockIdx.x*256 + threadIdx.x;   // < 524288
    int d  = fidx >> 18;
    int r  = fidx & 262143;
    int k2 = r >> 11;
    int r2 = r & 2047;
    int j  = r2 >> 1;
    int p  = r2 & 1;
    const float* w = d ? whh_b : whh_f;
    whhp[fidx] = (f16)w[(long)j*HDIM + 2*k2 + p];
}

// ---- embedding gather, f16, row m = t*64+b, padded to KP
__global__ void k_gather(const int* __restrict__ sentence, const float* __restrict__ embed,
                         f16* __restrict__ xg) {
    int m = blockIdx.x;
    int t = m >> 6, b = m & 63;
    int tok = sentence[b*SEQ + t];
    const float* row = embed + (long)tok*EDIM;
    for (int e = threadIdx.x; e < KP; e += 64)
        xg[(long)m*KP + e] = (e < EDIM) ? (f16)row[e] : (f16)0.f;
}

// ---- xproj = xg @ wpack^T + bias2, f16 MFMA GEMM, M=32768 N=2048 K=320
__launch_bounds__(256)
__global__ void k_gemm_xproj(const f16* __restrict__ xg, const f16* __restrict__ wpack,
                             const float* __restrict__ bias2, f16* __restrict__ xproj) {
    __shared__ __align__(16) f16 As[128*40];
    __shared__ __align__(16) f16 Bs[128*40];
    int tid = threadIdx.x;
    int bm = blockIdx.x, bn = blockIdx.y;
    int wid = tid >> 6, lane = tid & 63;
    int waveM = wid & 1, waveN = wid >> 1;
    int quad = lane >> 4, mlo = lane & 15;
    floatx4 acc[4][4] = {};
    for (int k0 = 0; k0 < KP; k0 += 32) {
        for (int it = 0; it < 2; ++it) {
            int c = tid + it*256;
            int row = c >> 2, ko = (c & 3)*8;
            *(uint4*)(&As[row*40 + ko]) = *(const uint4*)(&xg[(long)(bm*128+row)*KP + k0 + ko]);
            *(uint4*)(&Bs[row*40 + ko]) = *(const uint4*)(&wpack[(long)(bn*128+row)*KP + k0 + ko]);
        }
        __syncthreads();
        half8_t af[4], bf[4];
        #pragma unroll
        for (int i = 0; i < 4; ++i)
            af[i] = *(const half8_t*)(&As[(waveM*64 + i*16 + mlo)*40 + quad*8]);
        #pragma unroll
        for (int j = 0; j < 4; ++j)
            bf[j] = *(const half8_t*)(&Bs[(waveN*64 + j*16 + mlo)*40 + quad*8]);
        #pragma unroll
        for (int i = 0; i < 4; ++i)
            #pragma unroll
            for (int j = 0; j < 4; ++j)
                acc[i][j] = __builtin_amdgcn_mfma_f32_16x16x32_f16(af[i], bf[j], acc[i][j], 0, 0, 0);
        __syncthreads();
    }
    #pragma unroll
    for (int i = 0; i < 4; ++i)
        #pragma unroll
        for (int j = 0; j < 4; ++j) {
            int col = bn*128 + waveN*64 + j*16 + mlo;
            float bv = bias2[col];
            #pragma unroll
            for (int r = 0; r < 4; ++r) {
                int row = bm*128 + waveM*64 + i*16 + quad*4 + r;
                xproj[(long)row*NB + col] = (f16)(acc[i][j][r] + bv);
            }
        }
}

// ---- LSTM recurrence: WG = (dir, batch). 1024 threads, thread = gate row j.
// Recurrent weights CU-resident: 88 f16-pairs in VGPRs + 36 pairs in LDS + 4 pairs
// streamed from L2 per step. h broadcast via 32 ds_read_b128 from LDS.
#define NREG 88
#define NLDS 36
__launch_bounds__(1024)
__global__ void k_recur(const f16* __restrict__ xproj, const f16* __restrict__ whhp,
                        f16* __restrict__ hcat) {
    __shared__ uint32_t wlds[NLDS*1024];   // 144 KB: k2 in [88,124), layout [k2][j]
    __shared__ uint4 hb2q[32];             // 256 h values as 128 f16-pairs
    __shared__ float gbuf[1024];           // gate preacts for epilogue handoff
    int dir = blockIdx.x & 1, b = blockIdx.x >> 1;
    int tid = threadIdx.x;                 // gate index j
    const uint32_t* wg = (const uint32_t*)whhp + (long)dir*131072 + tid;
    uint32_t wreg[NREG];
    #pragma unroll
    for (int i = 0; i < NREG; ++i) wreg[i] = wg[(long)i*1024];
    #pragma unroll
    for (int i = 0; i < NLDS; ++i) wlds[i*1024 + tid] = wg[(long)(NREG+i)*1024];
    const uint32_t* wg4 = wg + (long)(NREG+NLDS)*1024;   // k2 = 124..127
    const f16* xcol = xproj + dir*G4H + tid;
    float c = 0.f;
    if (tid < 32) hb2q[tid] = make_uint4(0,0,0,0);
    __syncthreads();
    for (int s = 0; s < SEQ; ++s) {
        int t = dir ? (SEQ-1-s) : s;
        long mrow = (long)t*64 + b;
        float xv = (float)xcol[mrow*NB];
        uint32_t w124 = wg4[0], w125 = wg4[1024], w126 = wg4[2048], w127 = wg4[3072];
        float a0=0.f, a1=0.f, a2=0.f, a3=0.f;
        #pragma unroll
        for (int q = 0; q < 22; ++q) {         // k2 = 0..87 (register weights)
            uint4 hv = hb2q[q];
            a0 = fdot2(wreg[4*q+0], hv.x, a0);
            a1 = fdot2(wreg[4*q+1], hv.y, a1);
            a2 = fdot2(wreg[4*q+2], hv.z, a2);
            a3 = fdot2(wreg[4*q+3], hv.w, a3);
        }
        #pragma unroll
        for (int q = 0; q < 9; ++q) {          // k2 = 88..123 (LDS weights)
            uint4 hv = hb2q[22+q];
            a0 = fdot2(wlds[(4*q+0)*1024+tid], hv.x, a0);
            a1 = fdot2(wlds[(4*q+1)*1024+tid], hv.y, a1);
            a2 = fdot2(wlds[(4*q+2)*1024+tid], hv.z, a2);
            a3 = fdot2(wlds[(4*q+3)*1024+tid], hv.w, a3);
        }
        {                                       // k2 = 124..127 (L2-streamed)
            uint4 hv = hb2q[31];
            a0 = fdot2(w124, hv.x, a0);
            a1 = fdot2(w125, hv.y, a1);
            a2 = fdot2(w126, hv.z, a2);
            a3 = fdot2(w127, hv.w, a3);
        }
        gbuf[tid] = a0 + a1 + a2 + a3 + xv;
        __syncthreads();                       // gbuf ready; hb2q reads done
        if (tid < HDIM) {
            float gi = gbuf[tid],        gf = gbuf[HDIM+tid];
            float gg = gbuf[2*HDIM+tid], go = gbuf[3*HDIM+tid];
            float si = 1.f/(1.f+__expf(-gi));
            float sf = 1.f/(1.f+__expf(-gf));
            float so = 1.f/(1.f+__expf(-go));
            c = sf*c + si*tanhf(gg);
            float h = so*tanhf(c);
            ((f16*)hb2q)[tid] = (f16)h;
            hcat[mrow*512 + dir*HDIM + tid] = (f16)h;
        }
        __syncthreads();                       // new h visible before next step
    }
}

// ---- emissions: one wave per (t,b) row; lanes split K=512; 9 shuffle-reduced dots
__launch_bounds__(256)
__global__ void k_emis(const f16* __restrict__ hcat, const float* __restrict__ w_out,
                       const float* __restrict__ b_out, float* __restrict__ emis) {
    int r = blockIdx.x*4 + (threadIdx.x >> 6);
    int lane = threadIdx.x & 63;
    float hv[8];
    #pragma unroll
    for (int i = 0; i < 8; ++i) hv[i] = (float)hcat[(long)r*512 + lane + i*64];
    for (int tag = 0; tag < TAGS; ++tag) {
        float acc = 0.f;
        #pragma unroll
        for (int i = 0; i < 8; ++i) acc += hv[i]*w_out[tag*512 + lane + i*64];
        for (int off = 32; off; off >>= 1) acc += __shfl_xor(acc, off);
        if (lane == 0) emis[(long)r*TAGS + tag] = acc + b_out[tag];
    }
}

// ---- CRF: one wave per batch row. Gold score (lane-parallel over t) + forward logZ
// (lanes 0..8 hold alpha[j], shuffle-broadcast logsumexp over 9 prev tags).
__launch_bounds__(256)
__global__ void k_crf(const float* __restrict__ emis, const int* __restrict__ tags,
                      const int* __restrict__ mask, const float* __restrict__ start_trans,
                      const float* __restrict__ end_trans, const float* __restrict__ trans,
                      float* __restrict__ out) {
    int b = blockIdx.x*4 + (threadIdx.x >> 6);
    int lane = threadIdx.x & 63;
    int len = 0;
    #pragma unroll
    for (int i = 0; i < 8; ++i) len += mask[b*SEQ + lane + i*64];
    for (int off = 32; off; off >>= 1) len += __shfl_xor(len, off);
    float sc = 0.f;
    for (int i = 0; i < 8; ++i) {
        int t = 1 + lane + i*64;
        if (t < SEQ && mask[b*SEQ + t]) {
            int tp = tags[b*SEQ + t - 1], tc = tags[b*SEQ + t];
            sc += trans[tp*TAGS + tc] + emis[(long)(t*64 + b)*TAGS + tc];
        }
    }
    for (int off = 32; off; off >>= 1) sc += __shfl_xor(sc, off);
    int tag0 = tags[b*SEQ];
    sc += start_trans[tag0] + emis[(long)b*TAGS + tag0];
    sc += end_trans[tags[b*SEQ + len - 1]];
    // logZ
    bool act = lane < TAGS;
    int j = act ? lane : 0;
    float tcol[TAGS];
    #pragma unroll
    for (int i = 0; i < TAGS; ++i) tcol[i] = trans[i*TAGS + j];
    float alpha = act ? (start_trans[j] + emis[(long)b*TAGS + j]) : -1e30f;
    for (int t = 1; t < SEQ; ++t) {
        int mt = mask[b*SEQ + t];
        float em = emis[(long)(t*64 + b)*TAGS + j];
        float v[TAGS], mx = -1e30f;
        #pragma unroll
        for (int i = 0; i < TAGS; ++i) { v[i] = __shfl(alpha, i) + tcol[i]; mx = fmaxf(mx, v[i]); }
        float ss = 0.f;
        #pragma unroll
        for (int i = 0; i < TAGS; ++i) ss += __expf(v[i] - mx);
        float nxt = mx + __logf(ss) + em;
        if (mt && act) alpha = nxt;
    }
    float fv = act ? (alpha + end_trans[j]) : -1e30f;
    float mx = fv;
    for (int off = 32; off; off >>= 1) mx = fmaxf(mx, __shfl_xor(mx, off));
    float ss = act ? __expf(fv - mx) : 0.f;
    for (int off = 32; off; off >>= 1) ss += __shfl_xor(ss, off);
    float logZ = mx + __logf(ss);
    if (lane == 0) atomicAdd(out, (logZ - sc) * (1.0f/BATCH));
}

extern "C" void kernel_launch(void* const* d_in, const int* in_sizes, int n_in,
                              void* d_out, int out_size, void* d_ws, size_t ws_size,
                              hipStream_t stream) {
    const int*   sentence    = (const int*)  d_in[0];
    const int*   tags        = (const int*)  d_in[1];
    const float* embed       = (const float*)d_in[2];
    const float* wih_f       = (const float*)d_in[3];
    const float* whh_f       = (const float*)d_in[4];
    const float* bih_f       = (const float*)d_in[5];
    const float* bhh_f       = (const float*)d_in[6];
    const float* wih_b       = (const float*)d_in[7];
    const float* whh_b       = (const float*)d_in[8];
    const float* bih_b       = (const float*)d_in[9];
    const float* bhh_b       = (const float*)d_in[10];
    const float* w_out       = (const float*)d_in[11];
    const float* b_out       = (const float*)d_in[12];
    const float* start_trans = (const float*)d_in[13];
    const float* end_trans   = (const float*)d_in[14];
    const float* trans       = (const float*)d_in[15];
    const int*   mask        = (const int*)  d_in[16];

    char* ws = (char*)d_ws;
    f16*   xg    = (f16*)ws;   ws += (size_t)MROWS*KP*2;      // 20.97 MB
    f16*   wpack = (f16*)ws;   ws += (size_t)NB*KP*2;         // 1.31 MB
    float* bias2 = (float*)ws; ws += (size_t)NB*4;            // 8 KB
    f16*   whhp  = (f16*)ws;   ws += (size_t)2*262144*2;      // 1.05 MB
    f16*   xproj = (f16*)ws;   ws += (size_t)MROWS*NB*2;      // 134.2 MB
    f16*   hcat  = (f16*)ws;   ws += (size_t)MROWS*512*2;     // 33.55 MB
    float* emis  = (float*)ws; ws += (size_t)MROWS*TAGS*4;    // 1.18 MB

    hipLaunchKernelGGL(k_pack_wih, dim3(NB), dim3(64), 0, stream,
                       wih_f, wih_b, bih_f, bhh_f, bih_b, bhh_b, wpack, bias2);
    hipLaunchKernelGGL(k_pack_whh, dim3(2048), dim3(256), 0, stream, whh_f, whh_b, whhp);
    hipLaunchKernelGGL(k_gather, dim3(MROWS), dim3(64), 0, stream, sentence, embed, xg);
    hipLaunchKernelGGL(k_gemm_xproj, dim3(256,16), dim3(256), 0, stream, xg, wpack, bias2, xproj);
    hipLaunchKernelGGL(k_recur, dim3(128), dim3(1024), 0, stream, xproj, whhp, hcat);
    hipLaunchKernelGGL(k_emis, dim3(MROWS/4), dim3(256), 0, stream, hcat, w_out, b_out, emis);
    hipMemsetAsync(d_out, 0, sizeof(float), stream);
    hipLaunchKernelGGL(k_crf, dim3(BATCH/4), dim3(256), 0, stream,
                       emis, tags, mask, start_trans, end_trans, trans, (float*)d_out);
}

// Round 3
// 1607.835 us; speedup vs baseline: 3.2553x; 1.0899x over previous
//
#include <hip/hip_runtime.h>
#include <hip/hip_bf16.h>
#include <stdint.h>

#define EDIM 300
#define KP   320      // padded E for MFMA K-loop
#define HDIM 256
#define G4H  1024
#define NB   2048     // both directions' gates
#define TAGS 9
#define BATCH 64
#define SEQ  512
#define MROWS (SEQ*BATCH)   // 32768

typedef _Float16 f16;
typedef _Float16 half2_t __attribute__((ext_vector_type(2)));
typedef _Float16 half8_t __attribute__((ext_vector_type(8)));
typedef float    floatx4 __attribute__((ext_vector_type(4)));

__device__ __forceinline__ float fdot2(uint32_t w, uint32_t h, float acc) {
#if __has_builtin(__builtin_amdgcn_fdot2)
    return __builtin_amdgcn_fdot2(__builtin_bit_cast(half2_t, w),
                                  __builtin_bit_cast(half2_t, h), acc, false);
#else
    half2_t a = __builtin_bit_cast(half2_t, w), b = __builtin_bit_cast(half2_t, h);
    return acc + (float)a[0]*(float)b[0] + (float)a[1]*(float)b[1];
#endif
}

#define RL(v, l) ((uint32_t)__builtin_amdgcn_readlane((int)(v), (l)))

__device__ __forceinline__ float fast_sigmoid(float x) {
    return __builtin_amdgcn_rcpf(1.f + __expf(-x));
}
__device__ __forceinline__ float fast_tanh(float x) {
    // 1 - 2/(e^{2x}+1); exact at +-inf via rcp(inf)=0
    return 1.f - 2.f*__builtin_amdgcn_rcpf(__expf(2.f*x) + 1.f);
}

// ---- pack input-projection weights [n<1024: wih_f | n>=1024: wih_b], K padded to 320, + fused bias
__global__ void k_pack_wih(const float* __restrict__ wih_f, const float* __restrict__ wih_b,
                           const float* __restrict__ bih_f, const float* __restrict__ bhh_f,
                           const float* __restrict__ bih_b, const float* __restrict__ bhh_b,
                           f16* __restrict__ wpack, float* __restrict__ bias2) {
    int n = blockIdx.x;
    const float* src = (n < G4H) ? (wih_f + (long)n*EDIM) : (wih_b + (long)(n-G4H)*EDIM);
    for (int k = threadIdx.x; k < KP; k += 64)
        wpack[(long)n*KP + k] = (k < EDIM) ? (f16)src[k] : (f16)0.f;
    if (threadIdx.x == 0)
        bias2[n] = (n < G4H) ? (bih_f[n] + bhh_f[n]) : (bih_b[n-G4H] + bhh_b[n-G4H]);
}

// ---- pack recurrent weights into [dir][k2][j][2] f16 (k-pairs for v_dot2, j coalesced)
__global__ void k_pack_whh(const float* __restrict__ whh_f, const float* __restrict__ whh_b,
                           f16* __restrict__ whhp) {
    int fidx = blockIdx.x*256 + threadIdx.x;   // < 524288
    int d  = fidx >> 18;
    int r  = fidx & 262143;
    int k2 = r >> 11;
    int r2 = r & 2047;
    int j  = r2 >> 1;
    int p  = r2 & 1;
    const float* w = d ? whh_b : whh_f;
    whhp[fidx] = (f16)w[(long)j*HDIM + 2*k2 + p];
}

// ---- embedding gather, f16, row m = t*64+b, padded to KP
__global__ void k_gather(const int* __restrict__ sentence, const float* __restrict__ embed,
                         f16* __restrict__ xg) {
    int m = blockIdx.x;
    int t = m >> 6, b = m & 63;
    int tok = sentence[b*SEQ + t];
    const float* row = embed + (long)tok*EDIM;
    for (int e = threadIdx.x; e < KP; e += 64)
        xg[(long)m*KP + e] = (e < EDIM) ? (f16)row[e] : (f16)0.f;
}

// ---- xproj = xg @ wpack^T + bias2, f16 MFMA GEMM, M=32768 N=2048 K=320
__launch_bounds__(256)
__global__ void k_gemm_xproj(const f16* __restrict__ xg, const f16* __restrict__ wpack,
                             const float* __restrict__ bias2, f16* __restrict__ xproj) {
    __shared__ __align__(16) f16 As[128*40];
    __shared__ __align__(16) f16 Bs[128*40];
    int tid = threadIdx.x;
    int bm = blockIdx.x, bn = blockIdx.y;
    int wid = tid >> 6, lane = tid & 63;
    int waveM = wid & 1, waveN = wid >> 1;
    int quad = lane >> 4, mlo = lane & 15;
    floatx4 acc[4][4] = {};
    for (int k0 = 0; k0 < KP; k0 += 32) {
        for (int it = 0; it < 2; ++it) {
            int c = tid + it*256;
            int row = c >> 2, ko = (c & 3)*8;
            *(uint4*)(&As[row*40 + ko]) = *(const uint4*)(&xg[(long)(bm*128+row)*KP + k0 + ko]);
            *(uint4*)(&Bs[row*40 + ko]) = *(const uint4*)(&wpack[(long)(bn*128+row)*KP + k0 + ko]);
        }
        __syncthreads();
        half8_t af[4], bf[4];
        #pragma unroll
        for (int i = 0; i < 4; ++i)
            af[i] = *(const half8_t*)(&As[(waveM*64 + i*16 + mlo)*40 + quad*8]);
        #pragma unroll
        for (int j = 0; j < 4; ++j)
            bf[j] = *(const half8_t*)(&Bs[(waveN*64 + j*16 + mlo)*40 + quad*8]);
        #pragma unroll
        for (int i = 0; i < 4; ++i)
            #pragma unroll
            for (int j = 0; j < 4; ++j)
                acc[i][j] = __builtin_amdgcn_mfma_f32_16x16x32_f16(af[i], bf[j], acc[i][j], 0, 0, 0);
        __syncthreads();
    }
    #pragma unroll
    for (int i = 0; i < 4; ++i)
        #pragma unroll
        for (int j = 0; j < 4; ++j) {
            int col = bn*128 + waveN*64 + j*16 + mlo;
            float bv = bias2[col];
            #pragma unroll
            for (int r = 0; r < 4; ++r) {
                int row = bm*128 + waveM*64 + i*16 + quad*4 + r;
                xproj[(long)row*NB + col] = (f16)(acc[i][j][r] + bv);
            }
        }
}

// ---- LSTM recurrence: WG = (dir, batch). 1024 threads, thread = gate row j.
// LDS-instruction-minimized: h-pairs arrive via ONE lane-distinct ds_read_b128
// per wave + v_readlane broadcast (SGPR feeds v_dot2). Weights: 96 pairs in
// VGPRs + 32 pairs as 8 x ds_read_b128 from LDS. 2 barriers/step.
#define NREG 96
__launch_bounds__(1024)
__global__ void k_recur(const f16* __restrict__ xproj, const f16* __restrict__ whhp,
                        f16* __restrict__ hcat) {
    __shared__ uint4 wldsq[8][1024];     // 128 KB: pairs 96+4q..96+4q+3 for gate tid
    __shared__ uint32_t hpair[128];      // 512 B: h as f16 pairs
    __shared__ float gbuf[1024];         // 4 KB: gate preacts
    int dir = blockIdx.x & 1, b = blockIdx.x >> 1;
    int tid = threadIdx.x;               // gate row j
    int lane = tid & 63;
    const uint32_t* wg = (const uint32_t*)whhp + (long)dir*131072 + tid;
    uint32_t wreg[NREG];
    #pragma unroll
    for (int i = 0; i < NREG; ++i) wreg[i] = wg[(long)i*1024];
    #pragma unroll
    for (int q = 0; q < 8; ++q) {
        uint4 wv;
        wv.x = wg[(long)(NREG+4*q+0)*1024];
        wv.y = wg[(long)(NREG+4*q+1)*1024];
        wv.z = wg[(long)(NREG+4*q+2)*1024];
        wv.w = wg[(long)(NREG+4*q+3)*1024];
        wldsq[q][tid] = wv;
    }
    const f16* xcol = xproj + dir*G4H + tid;
    float c0 = 0.f, c1 = 0.f;
    if (tid < 128) hpair[tid] = 0u;
    __syncthreads();
    float xv = (float)xcol[(long)((dir ? SEQ-1 : 0)*64 + b)*NB];
    for (int s = 0; s < SEQ; ++s) {
        int t = dir ? (SEQ-1-s) : s;
        int sn = (s+1 < SEQ) ? s+1 : s;
        int tn = dir ? (SEQ-1-sn) : sn;
        long mrow = (long)t*64 + b;
        float xnext = (float)xcol[((long)tn*64 + b)*NB];   // prefetch next step
        uint4 hq = ((const uint4*)hpair)[lane & 31];       // lane L holds pairs 4L..4L+3
        float a0=0.f, a1=0.f, a2=0.f, a3=0.f;
        #pragma unroll
        for (int qq = 0; qq < NREG/4; ++qq) {              // pairs 0..95 (VGPR weights)
            uint32_t h0 = RL(hq.x, qq);
            uint32_t h1 = RL(hq.y, qq);
            uint32_t h2 = RL(hq.z, qq);
            uint32_t h3 = RL(hq.w, qq);
            a0 = fdot2(wreg[4*qq+0], h0, a0);
            a1 = fdot2(wreg[4*qq+1], h1, a1);
            a2 = fdot2(wreg[4*qq+2], h2, a2);
            a3 = fdot2(wreg[4*qq+3], h3, a3);
        }
        #pragma unroll
        for (int q = 0; q < 8; ++q) {                      // pairs 96..127 (LDS weights, b128)
            uint4 wv = wldsq[q][tid];
            int qq = NREG/4 + q;
            uint32_t h0 = RL(hq.x, qq);
            uint32_t h1 = RL(hq.y, qq);
            uint32_t h2 = RL(hq.z, qq);
            uint32_t h3 = RL(hq.w, qq);
            a0 = fdot2(wv.x, h0, a0);
            a1 = fdot2(wv.y, h1, a1);
            a2 = fdot2(wv.z, h2, a2);
            a3 = fdot2(wv.w, h3, a3);
        }
        gbuf[tid] = a0 + a1 + a2 + a3 + xv;
        xv = xnext;
        __syncthreads();                 // gbuf complete; hq reads done
        if (tid < 128) {
            int u = 2*tid;
            float2 I = *(const float2*)&gbuf[u];
            float2 F = *(const float2*)&gbuf[HDIM + u];
            float2 G = *(const float2*)&gbuf[2*HDIM + u];
            float2 O = *(const float2*)&gbuf[3*HDIM + u];
            c0 = fast_sigmoid(F.x)*c0 + fast_sigmoid(I.x)*fast_tanh(G.x);
            c1 = fast_sigmoid(F.y)*c1 + fast_sigmoid(I.y)*fast_tanh(G.y);
            float h0 = fast_sigmoid(O.x)*fast_tanh(c0);
            float h1 = fast_sigmoid(O.y)*fast_tanh(c1);
            f16 h0h = (f16)h0, h1h = (f16)h1;
            uint32_t packed = (uint32_t)__builtin_bit_cast(uint16_t, h0h)
                            | ((uint32_t)__builtin_bit_cast(uint16_t, h1h) << 16);
            hpair[tid] = packed;
            *(uint32_t*)&hcat[mrow*512 + dir*HDIM + u] = packed;
        }
        __syncthreads();                 // new h visible before next step
    }
}

// ---- emissions: one wave per (t,b) row; lanes split K=512; 9 shuffle-reduced dots
__launch_bounds__(256)
__global__ void k_emis(const f16* __restrict__ hcat, const float* __restrict__ w_out,
                       const float* __restrict__ b_out, float* __restrict__ emis) {
    int r = blockIdx.x*4 + (threadIdx.x >> 6);
    int lane = threadIdx.x & 63;
    float hv[8];
    #pragma unroll
    for (int i = 0; i < 8; ++i) hv[i] = (float)hcat[(long)r*512 + lane + i*64];
    for (int tag = 0; tag < TAGS; ++tag) {
        float acc = 0.f;
        #pragma unroll
        for (int i = 0; i < 8; ++i) acc += hv[i]*w_out[tag*512 + lane + i*64];
        for (int off = 32; off; off >>= 1) acc += __shfl_xor(acc, off);
        if (lane == 0) emis[(long)r*TAGS + tag] = acc + b_out[tag];
    }
}

// ---- CRF: one wave per batch row. Gold score (lane-parallel over t) + forward logZ
// (lanes 0..8 hold alpha[j], shuffle-broadcast logsumexp over 9 prev tags).
__launch_bounds__(256)
__global__ void k_crf(const float* __restrict__ emis, const int* __restrict__ tags,
                      const int* __restrict__ mask, const float* __restrict__ start_trans,
                      const float* __restrict__ end_trans, const float* __restrict__ trans,
                      float* __restrict__ out) {
    int b = blockIdx.x*4 + (threadIdx.x >> 6);
    int lane = threadIdx.x & 63;
    int len = 0;
    #pragma unroll
    for (int i = 0; i < 8; ++i) len += mask[b*SEQ + lane + i*64];
    for (int off = 32; off; off >>= 1) len += __shfl_xor(len, off);
    float sc = 0.f;
    for (int i = 0; i < 8; ++i) {
        int t = 1 + lane + i*64;
        if (t < SEQ && mask[b*SEQ + t]) {
            int tp = tags[b*SEQ + t - 1], tc = tags[b*SEQ + t];
            sc += trans[tp*TAGS + tc] + emis[(long)(t*64 + b)*TAGS + tc];
        }
    }
    for (int off = 32; off; off >>= 1) sc += __shfl_xor(sc, off);
    int tag0 = tags[b*SEQ];
    sc += start_trans[tag0] + emis[(long)b*TAGS + tag0];
    sc += end_trans[tags[b*SEQ + len - 1]];
    // logZ
    bool act = lane < TAGS;
    int j = act ? lane : 0;
    float tcol[TAGS];
    #pragma unroll
    for (int i = 0; i < TAGS; ++i) tcol[i] = trans[i*TAGS + j];
    float alpha = act ? (start_trans[j] + emis[(long)b*TAGS + j]) : -1e30f;
    for (int t = 1; t < SEQ; ++t) {
        int mt = mask[b*SEQ + t];
        float em = emis[(long)(t*64 + b)*TAGS + j];
        float v[TAGS], mx = -1e30f;
        #pragma unroll
        for (int i = 0; i < TAGS; ++i) { v[i] = __shfl(alpha, i) + tcol[i]; mx = fmaxf(mx, v[i]); }
        float ss = 0.f;
        #pragma unroll
        for (int i = 0; i < TAGS; ++i) ss += __expf(v[i] - mx);
        float nxt = mx + __logf(ss) + em;
        if (mt && act) alpha = nxt;
    }
    float fv = act ? (alpha + end_trans[j]) : -1e30f;
    float mx = fv;
    for (int off = 32; off; off >>= 1) mx = fmaxf(mx, __shfl_xor(mx, off));
    float ss = act ? __expf(fv - mx) : 0.f;
    for (int off = 32; off; off >>= 1) ss += __shfl_xor(ss, off);
    float logZ = mx + __logf(ss);
    if (lane == 0) atomicAdd(out, (logZ - sc) * (1.0f/BATCH));
}

extern "C" void kernel_launch(void* const* d_in, const int* in_sizes, int n_in,
                              void* d_out, int out_size, void* d_ws, size_t ws_size,
                              hipStream_t stream) {
    const int*   sentence    = (const int*)  d_in[0];
    const int*   tags        = (const int*)  d_in[1];
    const float* embed       = (const float*)d_in[2];
    const float* wih_f       = (const float*)d_in[3];
    const float* whh_f       = (const float*)d_in[4];
    const float* bih_f       = (const float*)d_in[5];
    const float* bhh_f       = (const float*)d_in[6];
    const float* wih_b       = (const float*)d_in[7];
    const float* whh_b       = (const float*)d_in[8];
    const float* bih_b       = (const float*)d_in[9];
    const float* bhh_b       = (const float*)d_in[10];
    const float* w_out       = (const float*)d_in[11];
    const float* b_out       = (const float*)d_in[12];
    const float* start_trans = (const float*)d_in[13];
    const float* end_trans   = (const float*)d_in[14];
    const float* trans       = (const float*)d_in[15];
    const int*   mask        = (const int*)  d_in[16];

    char* ws = (char*)d_ws;
    f16*   xg    = (f16*)ws;   ws += (size_t)MROWS*KP*2;      // 20.97 MB
    f16*   wpack = (f16*)ws;   ws += (size_t)NB*KP*2;         // 1.31 MB
    float* bias2 = (float*)ws; ws += (size_t)NB*4;            // 8 KB
    f16*   whhp  = (f16*)ws;   ws += (size_t)2*262144*2;      // 1.05 MB
    f16*   xproj = (f16*)ws;   ws += (size_t)MROWS*NB*2;      // 134.2 MB
    f16*   hcat  = (f16*)ws;   ws += (size_t)MROWS*512*2;     // 33.55 MB
    float* emis  = (float*)ws; ws += (size_t)MROWS*TAGS*4;    // 1.18 MB

    hipLaunchKernelGGL(k_pack_wih, dim3(NB), dim3(64), 0, stream,
                       wih_f, wih_b, bih_f, bhh_f, bih_b, bhh_b, wpack, bias2);
    hipLaunchKernelGGL(k_pack_whh, dim3(2048), dim3(256), 0, stream, whh_f, whh_b, whhp);
    hipLaunchKernelGGL(k_gather, dim3(MROWS), dim3(64), 0, stream, sentence, embed, xg);
    hipLaunchKernelGGL(k_gemm_xproj, dim3(256,16), dim3(256), 0, stream, xg, wpack, bias2, xproj);
    hipLaunchKernelGGL(k_recur, dim3(128), dim3(1024), 0, stream, xproj, whhp, hcat);
    hipLaunchKernelGGL(k_emis, dim3(MROWS/4), dim3(256), 0, stream, hcat, w_out, b_out, emis);
    hipMemsetAsync(d_out, 0, sizeof(float), stream);
    hipLaunchKernelGGL(k_crf, dim3(BATCH/4), dim3(256), 0, stream,
                       emis, tags, mask, start_trans, end_trans, trans, (float*)d_out);
}

// Round 4
// 1303.685 us; speedup vs baseline: 4.0147x; 1.2333x over previous
//
#include <hip/hip_runtime.h>
#include <hip/hip_bf16.h>
#include <stdint.h>

#define EDIM 300
#define KP   320      // padded E for MFMA K-loop
#define HDIM 256
#define G4H  1024
#define NB   2048     // both directions' gates
#define TAGS 9
#define BATCH 64
#define SEQ  512
#define MROWS (SEQ*BATCH)   // 32768

typedef _Float16 f16;
typedef _Float16 half2_t __attribute__((ext_vector_type(2)));
typedef _Float16 half8_t __attribute__((ext_vector_type(8)));
typedef float    floatx4 __attribute__((ext_vector_type(4)));

__device__ __forceinline__ float fdot2(uint32_t w, uint32_t h, float acc) {
#if __has_builtin(__builtin_amdgcn_fdot2)
    return __builtin_amdgcn_fdot2(__builtin_bit_cast(half2_t, w),
                                  __builtin_bit_cast(half2_t, h), acc, false);
#else
    half2_t a = __builtin_bit_cast(half2_t, w), b = __builtin_bit_cast(half2_t, h);
    return acc + (float)a[0]*(float)b[0] + (float)a[1]*(float)b[1];
#endif
}

#define RL(v, l) ((uint32_t)__builtin_amdgcn_readlane((int)(v), (l)))

__device__ __forceinline__ float fast_sigmoid(float x) {
    return __builtin_amdgcn_rcpf(1.f + __expf(-x));
}
__device__ __forceinline__ float fast_tanh(float x) {
    // 1 - 2/(e^{2x}+1); exact at +-inf via rcp(inf)=0
    return 1.f - 2.f*__builtin_amdgcn_rcpf(__expf(2.f*x) + 1.f);
}

// ---- pack input-projection weights [n<1024: wih_f | n>=1024: wih_b], K padded to 320, + fused bias
__global__ void k_pack_wih(const float* __restrict__ wih_f, const float* __restrict__ wih_b,
                           const float* __restrict__ bih_f, const float* __restrict__ bhh_f,
                           const float* __restrict__ bih_b, const float* __restrict__ bhh_b,
                           f16* __restrict__ wpack, float* __restrict__ bias2) {
    int n = blockIdx.x;
    const float* src = (n < G4H) ? (wih_f + (long)n*EDIM) : (wih_b + (long)(n-G4H)*EDIM);
    for (int k = threadIdx.x; k < KP; k += 64)
        wpack[(long)n*KP + k] = (k < EDIM) ? (f16)src[k] : (f16)0.f;
    if (threadIdx.x == 0)
        bias2[n] = (n < G4H) ? (bih_f[n] + bhh_f[n]) : (bih_b[n-G4H] + bhh_b[n-G4H]);
}

// ---- pack recurrent weights into [dir][k2][j][2] f16 (k-pairs for v_dot2, j coalesced)
__global__ void k_pack_whh(const float* __restrict__ whh_f, const float* __restrict__ whh_b,
                           f16* __restrict__ whhp) {
    int fidx = blockIdx.x*256 + threadIdx.x;   // < 524288
    int d  = fidx >> 18;
    int r  = fidx & 262143;
    int k2 = r >> 11;
    int r2 = r & 2047;
    int j  = r2 >> 1;
    int p  = r2 & 1;
    const float* w = d ? whh_b : whh_f;
    whhp[fidx] = (f16)w[(long)j*HDIM + 2*k2 + p];
}

// ---- embedding gather, f16, row m = t*64+b, padded to KP
__global__ void k_gather(const int* __restrict__ sentence, const float* __restrict__ embed,
                         f16* __restrict__ xg) {
    int m = blockIdx.x;
    int t = m >> 6, b = m & 63;
    int tok = sentence[b*SEQ + t];
    const float* row = embed + (long)tok*EDIM;
    for (int e = threadIdx.x; e < KP; e += 64)
        xg[(long)m*KP + e] = (e < EDIM) ? (f16)row[e] : (f16)0.f;
}

// ---- xproj = xg @ wpack^T + bias2, f16 MFMA GEMM, M=32768 N=2048 K=320
__launch_bounds__(256)
__global__ void k_gemm_xproj(const f16* __restrict__ xg, const f16* __restrict__ wpack,
                             const float* __restrict__ bias2, f16* __restrict__ xproj) {
    __shared__ __align__(16) f16 As[128*40];
    __shared__ __align__(16) f16 Bs[128*40];
    int tid = threadIdx.x;
    int bm = blockIdx.x, bn = blockIdx.y;
    int wid = tid >> 6, lane = tid & 63;
    int waveM = wid & 1, waveN = wid >> 1;
    int quad = lane >> 4, mlo = lane & 15;
    floatx4 acc[4][4] = {};
    for (int k0 = 0; k0 < KP; k0 += 32) {
        for (int it = 0; it < 2; ++it) {
            int c = tid + it*256;
            int row = c >> 2, ko = (c & 3)*8;
            *(uint4*)(&As[row*40 + ko]) = *(const uint4*)(&xg[(long)(bm*128+row)*KP + k0 + ko]);
            *(uint4*)(&Bs[row*40 + ko]) = *(const uint4*)(&wpack[(long)(bn*128+row)*KP + k0 + ko]);
        }
        __syncthreads();
        half8_t af[4], bf[4];
        #pragma unroll
        for (int i = 0; i < 4; ++i)
            af[i] = *(const half8_t*)(&As[(waveM*64 + i*16 + mlo)*40 + quad*8]);
        #pragma unroll
        for (int j = 0; j < 4; ++j)
            bf[j] = *(const half8_t*)(&Bs[(waveN*64 + j*16 + mlo)*40 + quad*8]);
        #pragma unroll
        for (int i = 0; i < 4; ++i)
            #pragma unroll
            for (int j = 0; j < 4; ++j)
                acc[i][j] = __builtin_amdgcn_mfma_f32_16x16x32_f16(af[i], bf[j], acc[i][j], 0, 0, 0);
        __syncthreads();
    }
    #pragma unroll
    for (int i = 0; i < 4; ++i)
        #pragma unroll
        for (int j = 0; j < 4; ++j) {
            int col = bn*128 + waveN*64 + j*16 + mlo;
            float bv = bias2[col];
            #pragma unroll
            for (int r = 0; r < 4; ++r) {
                int row = bm*128 + waveM*64 + i*16 + quad*4 + r;
                xproj[(long)row*NB + col] = (f16)(acc[i][j][r] + bv);
            }
        }
}

// ---- LSTM recurrence: WG = (dir, batch), 512 threads, 2 gate rows per thread.
// tid<256: rows (u, u+256) = (i,f) of unit u; tid>=256: rows (u+512, u+768) = (g,o).
// 104 weight pairs/row pinned in VGPRs (asm fence blocks rematerialization),
// 24 pairs/row in LDS via ds_read_b128. h: 1 ds_read_b128 + readlane broadcast
// shared by both rows. Epilogue is barrier-exchange of (i,f)/(g,o) float2s.
#define NREG 104
#define NLQ  6      // LDS uint4-quads per row (24 pairs)
__launch_bounds__(512, 2)
__global__ void k_recur(const f16* __restrict__ xproj, const f16* __restrict__ whhp,
                        f16* __restrict__ hcat) {
    __shared__ uint4 wlds[2*NLQ][512];   // 96 KB
    __shared__ uint32_t hpair[128];      // h as f16 pairs
    __shared__ float2 gbuf[512];         // (i,f) then (g,o) preacts
    int dir = blockIdx.x & 1, b = blockIdx.x >> 1;
    int tid = threadIdx.x, lane = tid & 63;
    int u = tid & 255, hs = tid >> 8;
    int rowA = hs ? (512 + u) : u;       // g : i
    int rowB = rowA + 256;               // o : f
    const uint32_t* base = (const uint32_t*)whhp + (long)dir*131072;
    const uint32_t* wgA = base + rowA;
    const uint32_t* wgB = base + rowB;
    uint32_t wregA[NREG], wregB[NREG];
    #pragma unroll
    for (int i = 0; i < NREG; ++i) { wregA[i] = wgA[(long)i*1024]; wregB[i] = wgB[(long)i*1024]; }
    #pragma unroll
    for (int i = 0; i < NREG; ++i) { asm volatile("" : "+v"(wregA[i]), "+v"(wregB[i])); }
    #pragma unroll
    for (int q = 0; q < NLQ; ++q) {
        uint4 wa, wb;
        wa.x = wgA[(long)(NREG+4*q+0)*1024]; wa.y = wgA[(long)(NREG+4*q+1)*1024];
        wa.z = wgA[(long)(NREG+4*q+2)*1024]; wa.w = wgA[(long)(NREG+4*q+3)*1024];
        wb.x = wgB[(long)(NREG+4*q+0)*1024]; wb.y = wgB[(long)(NREG+4*q+1)*1024];
        wb.z = wgB[(long)(NREG+4*q+2)*1024]; wb.w = wgB[(long)(NREG+4*q+3)*1024];
        wlds[q][tid] = wa;
        wlds[NLQ+q][tid] = wb;
    }
    const f16* xA = xproj + dir*G4H + rowA;
    const f16* xB = xproj + dir*G4H + rowB;
    float c = 0.f;
    if (tid < 128) hpair[tid] = 0u;
    __syncthreads();
    long m0 = (long)((dir ? SEQ-1 : 0)*64 + b);
    float xvA = (float)xA[m0*NB], xvB = (float)xB[m0*NB];
    for (int s = 0; s < SEQ; ++s) {
        int t = dir ? (SEQ-1-s) : s;
        int sn = (s+1 < SEQ) ? s+1 : s;
        int tn = dir ? (SEQ-1-sn) : sn;
        long mrow = (long)t*64 + b;
        long mnext = (long)tn*64 + b;
        float xnA = (float)xA[mnext*NB], xnB = (float)xB[mnext*NB];  // prefetch
        uint4 hq = ((const uint4*)hpair)[lane & 31];   // lane L: pairs 4L..4L+3
        float aA0=0.f, aA1=0.f, aB0=0.f, aB1=0.f;
        #pragma unroll
        for (int qq = 0; qq < NREG/4; ++qq) {          // pairs 0..103 (VGPR weights)
            uint32_t h0 = RL(hq.x, qq), h1 = RL(hq.y, qq);
            uint32_t h2 = RL(hq.z, qq), h3 = RL(hq.w, qq);
            aA0 = fdot2(wregA[4*qq+0], h0, aA0); aB0 = fdot2(wregB[4*qq+0], h0, aB0);
            aA1 = fdot2(wregA[4*qq+1], h1, aA1); aB1 = fdot2(wregB[4*qq+1], h1, aB1);
            aA0 = fdot2(wregA[4*qq+2], h2, aA0); aB0 = fdot2(wregB[4*qq+2], h2, aB0);
            aA1 = fdot2(wregA[4*qq+3], h3, aA1); aB1 = fdot2(wregB[4*qq+3], h3, aB1);
        }
        #pragma unroll
        for (int q = 0; q < NLQ; ++q) {                // pairs 104..127 (LDS weights)
            int qq = NREG/4 + q;
            uint4 wa = wlds[q][tid], wb = wlds[NLQ+q][tid];
            uint32_t h0 = RL(hq.x, qq), h1 = RL(hq.y, qq);
            uint32_t h2 = RL(hq.z, qq), h3 = RL(hq.w, qq);
            aA0 = fdot2(wa.x, h0, aA0); aB0 = fdot2(wb.x, h0, aB0);
            aA1 = fdot2(wa.y, h1, aA1); aB1 = fdot2(wb.y, h1, aB1);
            aA0 = fdot2(wa.z, h2, aA0); aB0 = fdot2(wb.z, h2, aB0);
            aA1 = fdot2(wa.w, h3, aA1); aB1 = fdot2(wb.w, h3, aB1);
        }
        gbuf[tid] = make_float2(aA0 + aA1 + xvA, aB0 + aB1 + xvB);
        xvA = xnA; xvB = xnB;
        __syncthreads();               // gbuf complete; hq reads done
        if (tid < 256) {
            float2 IF = gbuf[tid];         // (i, f) of unit tid
            float2 GO = gbuf[256 + tid];   // (g, o) of unit tid
            float si = fast_sigmoid(IF.x), sf = fast_sigmoid(IF.y);
            float so = fast_sigmoid(GO.y);
            c = sf*c + si*fast_tanh(GO.x);
            float h = so*fast_tanh(c);
            f16 hh = (f16)h;
            ((f16*)hpair)[tid] = hh;
            hcat[mrow*512 + dir*HDIM + tid] = hh;
        }
        __syncthreads();               // new h visible before next step
    }
}

// ---- emissions: one wave per (t,b) row; lanes split K=512; 9 shuffle-reduced dots
__launch_bounds__(256)
__global__ void k_emis(const f16* __restrict__ hcat, const float* __restrict__ w_out,
                       const float* __restrict__ b_out, float* __restrict__ emis) {
    int r = blockIdx.x*4 + (threadIdx.x >> 6);
    int lane = threadIdx.x & 63;
    float hv[8];
    #pragma unroll
    for (int i = 0; i < 8; ++i) hv[i] = (float)hcat[(long)r*512 + lane + i*64];
    for (int tag = 0; tag < TAGS; ++tag) {
        float acc = 0.f;
        #pragma unroll
        for (int i = 0; i < 8; ++i) acc += hv[i]*w_out[tag*512 + lane + i*64];
        for (int off = 32; off; off >>= 1) acc += __shfl_xor(acc, off);
        if (lane == 0) emis[(long)r*TAGS + tag] = acc + b_out[tag];
    }
}

// ---- CRF: one wave per batch row. Gold score (lane-parallel over t) + forward logZ
// (lanes 0..8 hold alpha[j], shuffle-broadcast logsumexp over 9 prev tags).
__launch_bounds__(256)
__global__ void k_crf(const float* __restrict__ emis, const int* __restrict__ tags,
                      const int* __restrict__ mask, const float* __restrict__ start_trans,
                      const float* __restrict__ end_trans, const float* __restrict__ trans,
                      float* __restrict__ out) {
    int b = blockIdx.x*4 + (threadIdx.x >> 6);
    int lane = threadIdx.x & 63;
    int len = 0;
    #pragma unroll
    for (int i = 0; i < 8; ++i) len += mask[b*SEQ + lane + i*64];
    for (int off = 32; off; off >>= 1) len += __shfl_xor(len, off);
    float sc = 0.f;
    for (int i = 0; i < 8; ++i) {
        int t = 1 + lane + i*64;
        if (t < SEQ && mask[b*SEQ + t]) {
            int tp = tags[b*SEQ + t - 1], tc = tags[b*SEQ + t];
            sc += trans[tp*TAGS + tc] + emis[(long)(t*64 + b)*TAGS + tc];
        }
    }
    for (int off = 32; off; off >>= 1) sc += __shfl_xor(sc, off);
    int tag0 = tags[b*SEQ];
    sc += start_trans[tag0] + emis[(long)b*TAGS + tag0];
    sc += end_trans[tags[b*SEQ + len - 1]];
    // logZ
    bool act = lane < TAGS;
    int j = act ? lane : 0;
    float tcol[TAGS];
    #pragma unroll
    for (int i = 0; i < TAGS; ++i) tcol[i] = trans[i*TAGS + j];
    float alpha = act ? (start_trans[j] + emis[(long)b*TAGS + j]) : -1e30f;
    for (int t = 1; t < SEQ; ++t) {
        int mt = mask[b*SEQ + t];
        float em = emis[(long)(t*64 + b)*TAGS + j];
        float v[TAGS], mx = -1e30f;
        #pragma unroll
        for (int i = 0; i < TAGS; ++i) { v[i] = __shfl(alpha, i) + tcol[i]; mx = fmaxf(mx, v[i]); }
        float ss = 0.f;
        #pragma unroll
        for (int i = 0; i < TAGS; ++i) ss += __expf(v[i] - mx);
        float nxt = mx + __logf(ss) + em;
        if (mt && act) alpha = nxt;
    }
    float fv = act ? (alpha + end_trans[j]) : -1e30f;
    float mx = fv;
    for (int off = 32; off; off >>= 1) mx = fmaxf(mx, __shfl_xor(mx, off));
    float ss = act ? __expf(fv - mx) : 0.f;
    for (int off = 32; off; off >>= 1) ss += __shfl_xor(ss, off);
    float logZ = mx + __logf(ss);
    if (lane == 0) atomicAdd(out, (logZ - sc) * (1.0f/BATCH));
}

extern "C" void kernel_launch(void* const* d_in, const int* in_sizes, int n_in,
                              void* d_out, int out_size, void* d_ws, size_t ws_size,
                              hipStream_t stream) {
    const int*   sentence    = (const int*)  d_in[0];
    const int*   tags        = (const int*)  d_in[1];
    const float* embed       = (const float*)d_in[2];
    const float* wih_f       = (const float*)d_in[3];
    const float* whh_f       = (const float*)d_in[4];
    const float* bih_f       = (const float*)d_in[5];
    const float* bhh_f       = (const float*)d_in[6];
    const float* wih_b       = (const float*)d_in[7];
    const float* whh_b       = (const float*)d_in[8];
    const float* bih_b       = (const float*)d_in[9];
    const float* bhh_b       = (const float*)d_in[10];
    const float* w_out       = (const float*)d_in[11];
    const float* b_out       = (const float*)d_in[12];
    const float* start_trans = (const float*)d_in[13];
    const float* end_trans   = (const float*)d_in[14];
    const float* trans       = (const float*)d_in[15];
    const int*   mask        = (const int*)  d_in[16];

    char* ws = (char*)d_ws;
    f16*   xg    = (f16*)ws;   ws += (size_t)MROWS*KP*2;      // 20.97 MB
    f16*   wpack = (f16*)ws;   ws += (size_t)NB*KP*2;         // 1.31 MB
    float* bias2 = (float*)ws; ws += (size_t)NB*4;            // 8 KB
    f16*   whhp  = (f16*)ws;   ws += (size_t)2*262144*2;      // 1.05 MB
    f16*   xproj = (f16*)ws;   ws += (size_t)MROWS*NB*2;      // 134.2 MB
    f16*   hcat  = (f16*)ws;   ws += (size_t)MROWS*512*2;     // 33.55 MB
    float* emis  = (float*)ws; ws += (size_t)MROWS*TAGS*4;    // 1.18 MB

    hipLaunchKernelGGL(k_pack_wih, dim3(NB), dim3(64), 0, stream,
                       wih_f, wih_b, bih_f, bhh_f, bih_b, bhh_b, wpack, bias2);
    hipLaunchKernelGGL(k_pack_whh, dim3(2048), dim3(256), 0, stream, whh_f, whh_b, whhp);
    hipLaunchKernelGGL(k_gather, dim3(MROWS), dim3(64), 0, stream, sentence, embed, xg);
    hipLaunchKernelGGL(k_gemm_xproj, dim3(256,16), dim3(256), 0, stream, xg, wpack, bias2, xproj);
    hipLaunchKernelGGL(k_recur, dim3(128), dim3(512), 0, stream, xproj, whhp, hcat);
    hipLaunchKernelGGL(k_emis, dim3(MROWS/4), dim3(256), 0, stream, hcat, w_out, b_out, emis);
    hipMemsetAsync(d_out, 0, sizeof(float), stream);
    hipLaunchKernelGGL(k_crf, dim3(BATCH/4), dim3(256), 0, stream,
                       emis, tags, mask, start_trans, end_trans, trans, (float*)d_out);
}